// Round 5
// baseline (60.806 us; speedup 1.0000x reference)
//
#include <hip/hip_runtime.h>

// out = Wv^T * X * Wv (softmax/log-Euclidean machinery collapses: wsum == 1).
// Pure-bf16 MFMA. X converted once (cooperatively) into LDS in A-fragment
// order with an XOR chunk swizzle; Wt fragments resident in VGPRs (stage-1 B
// fragment of wave w == Wt[w], so no separate Bv set); stage1->stage2
// transposition through a wave-private LDS scratch. 48 KiB LDS + VGPR<=170
// -> 3 blocks/CU (12 waves/CU) for latency hiding.

typedef unsigned int uint;
typedef unsigned short ushort;
typedef __bf16 bf16x8 __attribute__((ext_vector_type(8)));
typedef float f32x4 __attribute__((ext_vector_type(4)));
typedef uint uint4v __attribute__((ext_vector_type(4)));
typedef uint uint2v __attribute__((ext_vector_type(2)));

#define DIN   128
#define DOUT  64
#define BLOCK 256
#define GRID  1024
#define ITERS 2

#define MFMA(a, b, c) __builtin_amdgcn_mfma_f32_16x16x32_bf16((a), (b), (c), 0, 0, 0)

__device__ __forceinline__ ushort f2bf(float x) {           // RNE, exact
    uint u = __builtin_bit_cast(uint, x);
    u += 0x7FFFu + ((u >> 16) & 1u);
    return (ushort)(u >> 16);
}
__device__ __forceinline__ uint pk2(float a, float b) {     // lo16=a, hi16=b
    return (uint)f2bf(a) | ((uint)f2bf(b) << 16);
}

extern "C" __global__ void __launch_bounds__(BLOCK, 3)
spd_v5_kernel(const float* __restrict__ x, const float* __restrict__ wv,
              float* __restrict__ out)
{
    __shared__ char smem[49152];
    char* Xs = smem;                        // 32 KB: X as A-fragments, swizzled
    const int t    = threadIdx.x;
    const int lane = t & 63;
    const int w    = t >> 6;                // wave 0..3: owns cols 16w..16w+15
    const int c    = lane & 15;
    const int g    = lane >> 4;
    char* Tt = smem + 32768 + w * 4096;     // 4 KB per wave, B-fragment order

    // ---- Wt fragments: Wt[idx][kb] holds Wv[k][16idx+c], k = 32kb+8g+j.
    // Doubles as: stage-2 A-operand (row m=16idx+c) AND stage-1 B-operand of
    // wave w (col n=16w+c) -> use Wt[w][kb] in stage 1.
    bf16x8 Wt[4][4];
#pragma unroll
    for (int idx = 0; idx < 4; ++idx)
#pragma unroll
        for (int kb = 0; kb < 4; ++kb) {
            float f[8];
#pragma unroll
            for (int j = 0; j < 8; ++j)
                f[j] = wv[(kb * 32 + g * 8 + j) * DOUT + (idx * 16 + c)];
            uint4v u;
#pragma unroll
            for (int e = 0; e < 4; ++e) u[e] = pk2(f[2 * e], f[2 * e + 1]);
            Wt[idx][kb] = __builtin_bit_cast(bf16x8, u);
        }

    // ---- X staging geometry: thread (rr=t>>4, jj=t&15) handles
    // X[16i+rr, 8jj..8jj+7] -> frag chunk (mt=i, kb=jj>>2, g=jj&3, c=rr);
    // chunk index within tile = rr*16 + (jj^rr)  (XOR kills bank conflicts)
    const int rr = t >> 4;
    const int jj = t & 15;
    const size_t xthr = (size_t)rr * DIN + jj * 8;       // floats; + i*2048
    const int wroff = (rr * 16 + (jj ^ rr)) * 16;        // bytes;  + i*4096
    const float* xsrc = x + (size_t)blockIdx.x * ITERS * (DIN * DIN);

    // prologue: stage matrix 0
#pragma unroll
    for (int i = 0; i < 8; ++i) {
        float4 v0 = *(const float4*)(xsrc + i * 2048 + xthr);
        float4 v1 = *(const float4*)(xsrc + i * 2048 + xthr + 4);
        uint4v u;
        u[0] = pk2(v0.x, v0.y); u[1] = pk2(v0.z, v0.w);
        u[2] = pk2(v1.x, v1.y); u[3] = pk2(v1.z, v1.w);
        *(uint4v*)(Xs + i * 4096 + wroff) = u;
    }
    __syncthreads();

    // stage-1 read offsets per kb (swizzle-matched to wroff)
    int rdoff[4];
#pragma unroll
    for (int kb = 0; kb < 4; ++kb)
        rdoff[kb] = c * 256 + ((kb * 4 + g) ^ c) * 16;

    for (int it = 0; it < ITERS; ++it) {
        const int mat = blockIdx.x * ITERS + it;

        // ---- stage 1: T = X * Wv  (Tacc[mt][r] = T[16mt+4g+r, 16w+c])
        f32x4 Tacc[8];
#pragma unroll
        for (int mt = 0; mt < 8; ++mt) {
            f32x4 acc = {0.f, 0.f, 0.f, 0.f};
#pragma unroll
            for (int kb = 0; kb < 4; ++kb) {
                bf16x8 Ah = *(const bf16x8*)(Xs + mt * 4096 + rdoff[kb]);
                acc = MFMA(Ah, Wt[w][kb], acc);
            }
            Tacc[mt] = acc;
        }
        __syncthreads();              // all waves done reading Xs

        // issue next-X loads now; consumed after stage 2 (latency hidden
        // under Tt transpose + stage-2 MFMAs; short VGPR live range)
        float4 nxt[16];
        if (it + 1 < ITERS) {
            const float* xn = xsrc + (size_t)(it + 1) * (DIN * DIN) + xthr;
#pragma unroll
            for (int i = 0; i < 8; ++i) {
                nxt[2 * i]     = *(const float4*)(xn + i * 2048);
                nxt[2 * i + 1] = *(const float4*)(xn + i * 2048 + 4);
            }
        }

        // ---- Tacc -> Tt (wave-private transposition into B-frag order)
        // lane holds T[k0..k0+3, 16w+c], k0 = 16mt+4g; target chunk
        // (kb'=k0>>5, sub=(k0>>3)&3, c), byte-in-chunk = (k0&7)*2
#pragma unroll
        for (int mt = 0; mt < 8; ++mt) {
            uint2v p;
            p[0] = pk2(Tacc[mt][0], Tacc[mt][1]);
            p[1] = pk2(Tacc[mt][2], Tacc[mt][3]);
            const int k0 = mt * 16 + g * 4;
            const int byte = (k0 >> 5) * 1024 + (((k0 >> 3) & 3) * 16 + c) * 16
                           + (k0 & 7) * 2;
            *(uint2v*)(Tt + byte) = p;
        }
        bf16x8 Bt[4];
#pragma unroll
        for (int kb = 0; kb < 4; ++kb)
            Bt[kb] = *(const bf16x8*)(Tt + kb * 1024 + lane * 16);

        // ---- stage 2: O = Wt * T  -> direct global stores
        float* ob = out + (size_t)mat * (DOUT * DOUT)
                  + (size_t)(g * 4) * DOUT + (w * 16 + c);
#pragma unroll
        for (int mt2 = 0; mt2 < 4; ++mt2) {
            f32x4 acc = {0.f, 0.f, 0.f, 0.f};
#pragma unroll
            for (int kb = 0; kb < 4; ++kb)
                acc = MFMA(Wt[mt2][kb], Bt[kb], acc);
#pragma unroll
            for (int r = 0; r < 4; ++r)
                ob[(size_t)(mt2 * 16 + r) * DOUT] = acc[r];
        }

        if (it + 1 < ITERS) {
#pragma unroll
            for (int i = 0; i < 8; ++i) {
                uint4v u;
                u[0] = pk2(nxt[2 * i].x,     nxt[2 * i].y);
                u[1] = pk2(nxt[2 * i].z,     nxt[2 * i].w);
                u[2] = pk2(nxt[2 * i + 1].x, nxt[2 * i + 1].y);
                u[3] = pk2(nxt[2 * i + 1].z, nxt[2 * i + 1].w);
                *(uint4v*)(Xs + i * 4096 + wroff) = u;
            }
            __syncthreads();          // Xs ready for next iteration
        }
    }
}

extern "C" void kernel_launch(void* const* d_in, const int* in_sizes, int n_in,
                              void* d_out, int out_size, void* d_ws, size_t ws_size,
                              hipStream_t stream)
{
    const float* x  = (const float*)d_in[0];   // (32,64,128,128) fp32
    const float* wv = (const float*)d_in[3];   // (128,64) fp32
    float* out = (float*)d_out;                // (2048,64,64) fp32

    (void)in_sizes; (void)n_in; (void)d_ws; (void)ws_size; (void)out_size;

    hipLaunchKernelGGL(spd_v5_kernel, dim3(GRID), dim3(BLOCK), 0, stream,
                       x, wv, out);
}

// Round 6
// 56.501 us; speedup vs baseline: 1.0762x; 1.0762x over previous
//
#include <hip/hip_runtime.h>

// out = Wv^T * X * Wv (softmax/log-Euclidean machinery collapses: wsum == 1).
// Pure-bf16 MFMA. X staged per-matrix into a DOUBLE-BUFFERED LDS region in
// A-fragment order (XOR chunk swizzle); Wt fragments resident in VGPRs
// (stage-1 B fragment of wave w == Wt[w]); stage1->stage2 transposition via
// wave-private LDS. One barrier per matrix. #pragma unroll 1 pins the loop
// so prefetch registers never co-live across iterations (round-5 spilled).

typedef unsigned int uint;
typedef unsigned short ushort;
typedef __bf16 bf16x8 __attribute__((ext_vector_type(8)));
typedef float f32x4 __attribute__((ext_vector_type(4)));
typedef uint uint4v __attribute__((ext_vector_type(4)));
typedef uint uint2v __attribute__((ext_vector_type(2)));

#define DIN   128
#define DOUT  64
#define BLOCK 256
#define GRID  512
#define ITERS 4

#define MFMA(a, b, c) __builtin_amdgcn_mfma_f32_16x16x32_bf16((a), (b), (c), 0, 0, 0)

__device__ __forceinline__ ushort f2bf(float x) {           // RNE, exact
    uint u = __builtin_bit_cast(uint, x);
    u += 0x7FFFu + ((u >> 16) & 1u);
    return (ushort)(u >> 16);
}
__device__ __forceinline__ uint pk2(float a, float b) {     // lo16=a, hi16=b
    return (uint)f2bf(a) | ((uint)f2bf(b) << 16);
}

extern "C" __global__ void __launch_bounds__(BLOCK, 2)
spd_v6_kernel(const float* __restrict__ x, const float* __restrict__ wv,
              float* __restrict__ out)
{
    __shared__ char smem[81920];            // Xs[2][32KB] | Tt[4][4KB]
    const int t    = threadIdx.x;
    const int lane = t & 63;
    const int w    = t >> 6;                // wave 0..3: owns cols 16w..16w+15
    const int c    = lane & 15;
    const int g    = lane >> 4;
    char* Tt = smem + 65536 + w * 4096;     // wave-private, B-fragment order

    // ---- X staging geometry: thread (rr=t>>4, jj=t&15) handles
    // X[16i+rr, 8jj..8jj+7] -> frag chunk (mt=i, kb=jj>>2, g=jj&3, c=rr);
    // chunk index within 4KB mt-tile = rr*16 + (jj^rr)  (XOR -> bank-clean)
    const int rr = t >> 4;
    const int jj = t & 15;
    const size_t xthr = (size_t)rr * DIN + jj * 8;       // floats; + i*2048
    const int wroff = (rr * 16 + (jj ^ rr)) * 16;        // bytes;  + i*4096
    const float* xsrc = x + (size_t)blockIdx.x * ITERS * (DIN * DIN);

    // prologue: issue matrix-0 loads first (latency covered by Wt setup)
    float4 pv[16];
#pragma unroll
    for (int i = 0; i < 8; ++i) {
        pv[2 * i]     = *(const float4*)(xsrc + i * 2048 + xthr);
        pv[2 * i + 1] = *(const float4*)(xsrc + i * 2048 + xthr + 4);
    }

    // ---- Wt fragments: Wt[idx][kb] = Wv[k][16idx+c], k = 32kb+8g+j.
    // Stage-2 A-operand (all idx) AND stage-1 B-operand of wave w (idx==w).
    bf16x8 Wt[4][4];
#pragma unroll
    for (int idx = 0; idx < 4; ++idx)
#pragma unroll
        for (int kb = 0; kb < 4; ++kb) {
            float f[8];
#pragma unroll
            for (int j = 0; j < 8; ++j)
                f[j] = wv[(kb * 32 + g * 8 + j) * DOUT + (idx * 16 + c)];
            uint4v u;
#pragma unroll
            for (int e = 0; e < 4; ++e) u[e] = pk2(f[2 * e], f[2 * e + 1]);
            Wt[idx][kb] = __builtin_bit_cast(bf16x8, u);
        }

    // write matrix 0 into buffer 0
#pragma unroll
    for (int i = 0; i < 8; ++i) {
        uint4v u;
        u[0] = pk2(pv[2 * i].x,     pv[2 * i].y);
        u[1] = pk2(pv[2 * i].z,     pv[2 * i].w);
        u[2] = pk2(pv[2 * i + 1].x, pv[2 * i + 1].y);
        u[3] = pk2(pv[2 * i + 1].z, pv[2 * i + 1].w);
        *(uint4v*)(smem + i * 4096 + wroff) = u;
    }
    __syncthreads();

    // stage-1 read offsets per kb (swizzle-matched to wroff)
    int rdoff[4];
#pragma unroll
    for (int kb = 0; kb < 4; ++kb)
        rdoff[kb] = c * 256 + ((kb * 4 + g) ^ c) * 16;

#pragma unroll 1
    for (int it = 0; it < ITERS; ++it) {
        const int mat = blockIdx.x * ITERS + it;
        char* Xcur = smem + ((it & 1) << 15);
        char* Xnxt = smem + (((it + 1) & 1) << 15);

        // issue next-matrix loads into regs (consumed after stage 1)
        float4 nxt[16];
        if (it + 1 < ITERS) {
            const float* xn = xsrc + (size_t)(it + 1) * (DIN * DIN) + xthr;
#pragma unroll
            for (int i = 0; i < 8; ++i) {
                nxt[2 * i]     = *(const float4*)(xn + i * 2048);
                nxt[2 * i + 1] = *(const float4*)(xn + i * 2048 + 4);
            }
        }

        // ---- stage 1: T = X * Wv  (Tacc[mt][r] = T[16mt+4g+r, 16w+c])
        f32x4 Tacc[8];
#pragma unroll
        for (int mt = 0; mt < 8; ++mt) {
            f32x4 acc = {0.f, 0.f, 0.f, 0.f};
#pragma unroll
            for (int kb = 0; kb < 4; ++kb) {
                bf16x8 Ah = *(const bf16x8*)(Xcur + mt * 4096 + rdoff[kb]);
                acc = MFMA(Ah, Wt[w][kb], acc);
            }
            Tacc[mt] = acc;
        }

        // ---- write next matrix into the other buffer (no reader this iter)
        if (it + 1 < ITERS) {
#pragma unroll
            for (int i = 0; i < 8; ++i) {
                uint4v u;
                u[0] = pk2(nxt[2 * i].x,     nxt[2 * i].y);
                u[1] = pk2(nxt[2 * i].z,     nxt[2 * i].w);
                u[2] = pk2(nxt[2 * i + 1].x, nxt[2 * i + 1].y);
                u[3] = pk2(nxt[2 * i + 1].z, nxt[2 * i + 1].w);
                *(uint4v*)(Xnxt + i * 4096 + wroff) = u;
            }
        }
        // ONE barrier per matrix: separates this iter's Xcur reads (above)
        // from next iter's writes to that buffer, and this iter's Xnxt
        // writes from next iter's reads of it.
        __syncthreads();

        // ---- Tacc -> Tt (wave-private transposition into B-frag order)
#pragma unroll
        for (int mt = 0; mt < 8; ++mt) {
            uint2v p;
            p[0] = pk2(Tacc[mt][0], Tacc[mt][1]);
            p[1] = pk2(Tacc[mt][2], Tacc[mt][3]);
            const int k0 = mt * 16 + g * 4;
            const int byte = (k0 >> 5) * 1024 + (((k0 >> 3) & 3) * 16 + c) * 16
                           + (k0 & 7) * 2;
            *(uint2v*)(Tt + byte) = p;
        }
        bf16x8 Bt[4];
#pragma unroll
        for (int kb = 0; kb < 4; ++kb)
            Bt[kb] = *(const bf16x8*)(Tt + kb * 1024 + lane * 16);

        // ---- stage 2: O = Wt * T  -> direct global stores
        float* ob = out + (size_t)mat * (DOUT * DOUT)
                  + (size_t)(g * 4) * DOUT + (w * 16 + c);
#pragma unroll
        for (int mt2 = 0; mt2 < 4; ++mt2) {
            f32x4 acc = {0.f, 0.f, 0.f, 0.f};
#pragma unroll
            for (int kb = 0; kb < 4; ++kb)
                acc = MFMA(Wt[mt2][kb], Bt[kb], acc);
#pragma unroll
            for (int r = 0; r < 4; ++r)
                ob[(size_t)(mt2 * 16 + r) * DOUT] = acc[r];
        }
    }
}

extern "C" void kernel_launch(void* const* d_in, const int* in_sizes, int n_in,
                              void* d_out, int out_size, void* d_ws, size_t ws_size,
                              hipStream_t stream)
{
    const float* x  = (const float*)d_in[0];   // (32,64,128,128) fp32
    const float* wv = (const float*)d_in[3];   // (128,64) fp32
    float* out = (float*)d_out;                // (2048,64,64) fp32

    (void)in_sizes; (void)n_in; (void)d_ws; (void)ws_size; (void)out_size;

    hipLaunchKernelGGL(spd_v6_kernel, dim3(GRID), dim3(BLOCK), 0, stream,
                       x, wv, out);
}

// Round 7
// 55.296 us; speedup vs baseline: 1.0996x; 1.0218x over previous
//
#include <hip/hip_runtime.h>

// out = Wv^T * X * Wv (softmax/log-Euclidean machinery collapses: wsum == 1).
// Pure-bf16 MFMA. X staged into DOUBLE-BUFFERED LDS in A-fragment order
// (XOR chunk swizzle); Wt fragments resident in VGPRs (stage-1 B fragment of
// wave w == Wt[w]); stage1->stage2 transposition via wave-private LDS.
// ONE barrier per matrix, placed right after the staging LDS-write.
// FULL UNROLL + lb(256,2): the allocator keeps the 64-reg prefetch array in
// VGPRs only in straight-line code (r5: lb(256,3) spilled; r6: unroll 1
// spilled; r4: full unroll + lb(256,2) did not).

typedef unsigned int uint;
typedef unsigned short ushort;
typedef __bf16 bf16x8 __attribute__((ext_vector_type(8)));
typedef float f32x4 __attribute__((ext_vector_type(4)));
typedef uint uint4v __attribute__((ext_vector_type(4)));
typedef uint uint2v __attribute__((ext_vector_type(2)));

#define DIN   128
#define DOUT  64
#define BLOCK 256
#define GRID  512
#define ITERS 4

#define MFMA(a, b, c) __builtin_amdgcn_mfma_f32_16x16x32_bf16((a), (b), (c), 0, 0, 0)

__device__ __forceinline__ ushort f2bf(float x) {           // RNE, exact
    uint u = __builtin_bit_cast(uint, x);
    u += 0x7FFFu + ((u >> 16) & 1u);
    return (ushort)(u >> 16);
}
__device__ __forceinline__ uint pk2(float a, float b) {     // lo16=a, hi16=b
    return (uint)f2bf(a) | ((uint)f2bf(b) << 16);
}

extern "C" __global__ void __launch_bounds__(BLOCK, 2)
spd_v7_kernel(const float* __restrict__ x, const float* __restrict__ wv,
              float* __restrict__ out)
{
    __shared__ char smem[81920];            // Xs[2][32KB] | Tt[4][4KB]
    const int t    = threadIdx.x;
    const int lane = t & 63;
    const int w    = t >> 6;                // wave 0..3: owns cols 16w..16w+15
    const int c    = lane & 15;
    const int g    = lane >> 4;
    char* Tt = smem + 65536 + w * 4096;     // wave-private, B-fragment order

    // ---- X staging geometry: thread (rr=t>>4, jj=t&15) handles
    // X[16i+rr, 8jj..8jj+7] -> frag chunk (mt=i, kb=jj>>2, g=jj&3, c=rr);
    // chunk index within 4KB mt-tile = rr*16 + (jj^rr)  (XOR -> bank-clean)
    const int rr = t >> 4;
    const int jj = t & 15;
    const size_t xthr = (size_t)rr * DIN + jj * 8;       // floats; + i*2048
    const int wroff = (rr * 16 + (jj ^ rr)) * 16;        // bytes;  + i*4096
    const float* xsrc = x + (size_t)blockIdx.x * ITERS * (DIN * DIN);

    // prologue: issue matrix-0 loads first (latency covered by Wt setup)
    float4 pv[16];
#pragma unroll
    for (int i = 0; i < 8; ++i) {
        pv[2 * i]     = *(const float4*)(xsrc + i * 2048 + xthr);
        pv[2 * i + 1] = *(const float4*)(xsrc + i * 2048 + xthr + 4);
    }

    // ---- Wt fragments: Wt[idx][kb] = Wv[k][16idx+c], k = 32kb+8g+j.
    // Stage-2 A-operand (all idx) AND stage-1 B-operand of wave w (idx==w).
    bf16x8 Wt[4][4];
#pragma unroll
    for (int idx = 0; idx < 4; ++idx)
#pragma unroll
        for (int kb = 0; kb < 4; ++kb) {
            float f[8];
#pragma unroll
            for (int j = 0; j < 8; ++j)
                f[j] = wv[(kb * 32 + g * 8 + j) * DOUT + (idx * 16 + c)];
            uint4v u;
#pragma unroll
            for (int e = 0; e < 4; ++e) u[e] = pk2(f[2 * e], f[2 * e + 1]);
            Wt[idx][kb] = __builtin_bit_cast(bf16x8, u);
        }

    // write matrix 0 into buffer 0
#pragma unroll
    for (int i = 0; i < 8; ++i) {
        uint4v u;
        u[0] = pk2(pv[2 * i].x,     pv[2 * i].y);
        u[1] = pk2(pv[2 * i].z,     pv[2 * i].w);
        u[2] = pk2(pv[2 * i + 1].x, pv[2 * i + 1].y);
        u[3] = pk2(pv[2 * i + 1].z, pv[2 * i + 1].w);
        *(uint4v*)(smem + i * 4096 + wroff) = u;
    }
    __syncthreads();

    // stage-1 read offsets per kb (swizzle-matched to wroff)
    int rdoff[4];
#pragma unroll
    for (int kb = 0; kb < 4; ++kb)
        rdoff[kb] = c * 256 + ((kb * 4 + g) ^ c) * 16;

#pragma unroll
    for (int it = 0; it < ITERS; ++it) {
        const int mat = blockIdx.x * ITERS + it;
        char* Xcur = smem + ((it & 1) << 15);
        char* Xnxt = smem + (((it + 1) & 1) << 15);

        // issue next-matrix loads into regs (consumed right after stage 1)
        float4 nxt[16];
        if (it + 1 < ITERS) {
            const float* xn = xsrc + (size_t)(it + 1) * (DIN * DIN) + xthr;
#pragma unroll
            for (int i = 0; i < 8; ++i) {
                nxt[2 * i]     = *(const float4*)(xn + i * 2048);
                nxt[2 * i + 1] = *(const float4*)(xn + i * 2048 + 4);
            }
        }

        // ---- stage 1: T = X * Wv  (Tacc[mt][r] = T[16mt+4g+r, 16w+c])
        f32x4 Tacc[8];
#pragma unroll
        for (int mt = 0; mt < 8; ++mt) {
            f32x4 acc = {0.f, 0.f, 0.f, 0.f};
#pragma unroll
            for (int kb = 0; kb < 4; ++kb) {
                bf16x8 Ah = *(const bf16x8*)(Xcur + mt * 4096 + rdoff[kb]);
                acc = MFMA(Ah, Wt[w][kb], acc);
            }
            Tacc[mt] = acc;
        }

        // ---- write next matrix into the other buffer; prev iter's barrier
        // already separates these writes from iter it-1's reads of it.
        if (it + 1 < ITERS) {
#pragma unroll
            for (int i = 0; i < 8; ++i) {
                uint4v u;
                u[0] = pk2(nxt[2 * i].x,     nxt[2 * i].y);
                u[1] = pk2(nxt[2 * i].z,     nxt[2 * i].w);
                u[2] = pk2(nxt[2 * i + 1].x, nxt[2 * i + 1].y);
                u[3] = pk2(nxt[2 * i + 1].z, nxt[2 * i + 1].w);
                *(uint4v*)(Xnxt + i * 4096 + wroff) = u;
            }
            // ONE barrier per matrix: after it, transpose+stage2+stores run
            // before the next stage-1 read, so the wait covers staging only.
            __syncthreads();
        }

        // ---- Tacc -> Tt (wave-private transposition into B-frag order)
#pragma unroll
        for (int mt = 0; mt < 8; ++mt) {
            uint2v p;
            p[0] = pk2(Tacc[mt][0], Tacc[mt][1]);
            p[1] = pk2(Tacc[mt][2], Tacc[mt][3]);
            const int k0 = mt * 16 + g * 4;
            const int byte = (k0 >> 5) * 1024 + (((k0 >> 3) & 3) * 16 + c) * 16
                           + (k0 & 7) * 2;
            *(uint2v*)(Tt + byte) = p;
        }
        bf16x8 Bt[4];
#pragma unroll
        for (int kb = 0; kb < 4; ++kb)
            Bt[kb] = *(const bf16x8*)(Tt + kb * 1024 + lane * 16);

        // ---- stage 2: O = Wt * T  -> direct global stores
        float* ob = out + (size_t)mat * (DOUT * DOUT)
                  + (size_t)(g * 4) * DOUT + (w * 16 + c);
#pragma unroll
        for (int mt2 = 0; mt2 < 4; ++mt2) {
            f32x4 acc = {0.f, 0.f, 0.f, 0.f};
#pragma unroll
            for (int kb = 0; kb < 4; ++kb)
                acc = MFMA(Wt[mt2][kb], Bt[kb], acc);
#pragma unroll
            for (int r = 0; r < 4; ++r)
                ob[(size_t)(mt2 * 16 + r) * DOUT] = acc[r];
        }
    }
}

extern "C" void kernel_launch(void* const* d_in, const int* in_sizes, int n_in,
                              void* d_out, int out_size, void* d_ws, size_t ws_size,
                              hipStream_t stream)
{
    const float* x  = (const float*)d_in[0];   // (32,64,128,128) fp32
    const float* wv = (const float*)d_in[3];   // (128,64) fp32
    float* out = (float*)d_out;                // (2048,64,64) fp32

    (void)in_sizes; (void)n_in; (void)d_ws; (void)ws_size; (void)out_size;

    hipLaunchKernelGGL(spd_v7_kernel, dim3(GRID), dim3(BLOCK), 0, stream,
                       x, wv, out);
}

// Round 8
// 32.293 us; speedup vs baseline: 1.8829x; 1.7123x over previous
//
#include <hip/hip_runtime.h>

// out = Wv^T * X * Wv (softmax/log-Euclidean machinery collapses: wsum == 1).
// Pure-bf16 MFMA. X staged into DOUBLE-BUFFERED LDS in A-fragment order
// (XOR chunk swizzle); stage-1 B fragments (Bv) and stage-2 A fragments (Wt)
// BOTH resident in VGPRs with COMPILE-TIME indices only -- r5's Wt[w][kb]
// (runtime w) demoted the whole array to scratch (rule #20), causing the
// 256 B/thread spill seen in r5/r6/r7. One barrier per matrix.

typedef unsigned int uint;
typedef unsigned short ushort;
typedef __bf16 bf16x8 __attribute__((ext_vector_type(8)));
typedef float f32x4 __attribute__((ext_vector_type(4)));
typedef uint uint4v __attribute__((ext_vector_type(4)));
typedef uint uint2v __attribute__((ext_vector_type(2)));

#define DIN   128
#define DOUT  64
#define BLOCK 256
#define GRID  512
#define ITERS 4

#define MFMA(a, b, c) __builtin_amdgcn_mfma_f32_16x16x32_bf16((a), (b), (c), 0, 0, 0)

__device__ __forceinline__ ushort f2bf(float x) {           // RNE, exact
    uint u = __builtin_bit_cast(uint, x);
    u += 0x7FFFu + ((u >> 16) & 1u);
    return (ushort)(u >> 16);
}
__device__ __forceinline__ uint pk2(float a, float b) {     // lo16=a, hi16=b
    return (uint)f2bf(a) | ((uint)f2bf(b) << 16);
}

extern "C" __global__ void __launch_bounds__(BLOCK, 2)
spd_v8_kernel(const float* __restrict__ x, const float* __restrict__ wv,
              float* __restrict__ out)
{
    __shared__ char smem[81920];            // Xs[2][32KB] | Tt[4][4KB]
    const int t    = threadIdx.x;
    const int lane = t & 63;
    const int w    = t >> 6;                // wave 0..3: owns cols 16w..16w+15
    const int c    = lane & 15;
    const int g    = lane >> 4;
    char* Tt = smem + 65536 + w * 4096;     // wave-private, B-fragment order

    // ---- X staging geometry: thread (rr=t>>4, jj=t&15) handles
    // X[16i+rr, 8jj..8jj+7] -> frag chunk (mt=i, kb=jj>>2, g=jj&3, c=rr);
    // chunk index within 4KB mt-tile = rr*16 + (jj^rr)  (XOR -> bank-clean)
    const int rr = t >> 4;
    const int jj = t & 15;
    const size_t xthr = (size_t)rr * DIN + jj * 8;       // floats; + i*2048
    const int wroff = (rr * 16 + (jj ^ rr)) * 16;        // bytes;  + i*4096
    const float* xsrc = x + (size_t)blockIdx.x * ITERS * (DIN * DIN);

    // prologue: issue matrix-0 loads first (latency covered by Wt/Bv setup)
    float4 pv[16];
#pragma unroll
    for (int i = 0; i < 8; ++i) {
        pv[2 * i]     = *(const float4*)(xsrc + i * 2048 + xthr);
        pv[2 * i + 1] = *(const float4*)(xsrc + i * 2048 + xthr + 4);
    }

    // ---- stage-1 B fragments: Bv[kb] = Wv[k][16w+c], k = 32kb+8g+j.
    // Separate from Wt so ALL register-array indices are compile-time.
    bf16x8 Bv[4];
#pragma unroll
    for (int kb = 0; kb < 4; ++kb) {
        float f[8];
#pragma unroll
        for (int j = 0; j < 8; ++j)
            f[j] = wv[(kb * 32 + g * 8 + j) * DOUT + (w * 16 + c)];
        uint4v u;
#pragma unroll
        for (int e = 0; e < 4; ++e) u[e] = pk2(f[2 * e], f[2 * e + 1]);
        Bv[kb] = __builtin_bit_cast(bf16x8, u);
    }
    // ---- stage-2 A fragments: Wt[mt2][kb] = Wv[k][16mt2+c]
    bf16x8 Wt[4][4];
#pragma unroll
    for (int mt2 = 0; mt2 < 4; ++mt2)
#pragma unroll
        for (int kb = 0; kb < 4; ++kb) {
            float f[8];
#pragma unroll
            for (int j = 0; j < 8; ++j)
                f[j] = wv[(kb * 32 + g * 8 + j) * DOUT + (mt2 * 16 + c)];
            uint4v u;
#pragma unroll
            for (int e = 0; e < 4; ++e) u[e] = pk2(f[2 * e], f[2 * e + 1]);
            Wt[mt2][kb] = __builtin_bit_cast(bf16x8, u);
        }

    // write matrix 0 into buffer 0
#pragma unroll
    for (int i = 0; i < 8; ++i) {
        uint4v u;
        u[0] = pk2(pv[2 * i].x,     pv[2 * i].y);
        u[1] = pk2(pv[2 * i].z,     pv[2 * i].w);
        u[2] = pk2(pv[2 * i + 1].x, pv[2 * i + 1].y);
        u[3] = pk2(pv[2 * i + 1].z, pv[2 * i + 1].w);
        *(uint4v*)(smem + i * 4096 + wroff) = u;
    }
    __syncthreads();

    // stage-1 read offsets per kb (swizzle-matched to wroff)
    int rdoff[4];
#pragma unroll
    for (int kb = 0; kb < 4; ++kb)
        rdoff[kb] = c * 256 + ((kb * 4 + g) ^ c) * 16;

#pragma unroll
    for (int it = 0; it < ITERS; ++it) {
        const int mat = blockIdx.x * ITERS + it;
        char* Xcur = smem + ((it & 1) << 15);
        char* Xnxt = smem + (((it + 1) & 1) << 15);

        // issue next-matrix loads into regs (consumed right after stage 1)
        float4 nxt[16];
        if (it + 1 < ITERS) {
            const float* xn = xsrc + (size_t)(it + 1) * (DIN * DIN) + xthr;
#pragma unroll
            for (int i = 0; i < 8; ++i) {
                nxt[2 * i]     = *(const float4*)(xn + i * 2048);
                nxt[2 * i + 1] = *(const float4*)(xn + i * 2048 + 4);
            }
        }

        // ---- stage 1: T = X * Wv  (Tacc[mt][r] = T[16mt+4g+r, 16w+c])
        f32x4 Tacc[8];
#pragma unroll
        for (int mt = 0; mt < 8; ++mt) {
            f32x4 acc = {0.f, 0.f, 0.f, 0.f};
#pragma unroll
            for (int kb = 0; kb < 4; ++kb) {
                bf16x8 Ah = *(const bf16x8*)(Xcur + mt * 4096 + rdoff[kb]);
                acc = MFMA(Ah, Bv[kb], acc);
            }
            Tacc[mt] = acc;
        }

        // ---- write next matrix into the other buffer; prev iter's barrier
        // separates these writes from iter it-1's reads of this buffer.
        if (it + 1 < ITERS) {
#pragma unroll
            for (int i = 0; i < 8; ++i) {
                uint4v u;
                u[0] = pk2(nxt[2 * i].x,     nxt[2 * i].y);
                u[1] = pk2(nxt[2 * i].z,     nxt[2 * i].w);
                u[2] = pk2(nxt[2 * i + 1].x, nxt[2 * i + 1].y);
                u[3] = pk2(nxt[2 * i + 1].z, nxt[2 * i + 1].w);
                *(uint4v*)(Xnxt + i * 4096 + wroff) = u;
            }
            // ONE barrier per matrix: after it, transpose+stage2+stores run
            // before the next stage-1 read, so the wait covers staging only.
            __syncthreads();
        }

        // ---- Tacc -> Tt (wave-private transposition into B-frag order)
#pragma unroll
        for (int mt = 0; mt < 8; ++mt) {
            uint2v p;
            p[0] = pk2(Tacc[mt][0], Tacc[mt][1]);
            p[1] = pk2(Tacc[mt][2], Tacc[mt][3]);
            const int k0 = mt * 16 + g * 4;
            const int byte = (k0 >> 5) * 1024 + (((k0 >> 3) & 3) * 16 + c) * 16
                           + (k0 & 7) * 2;
            *(uint2v*)(Tt + byte) = p;
        }
        bf16x8 Bt[4];
#pragma unroll
        for (int kb = 0; kb < 4; ++kb)
            Bt[kb] = *(const bf16x8*)(Tt + kb * 1024 + lane * 16);

        // ---- stage 2: O = Wt * T  -> direct global stores
        float* ob = out + (size_t)mat * (DOUT * DOUT)
                  + (size_t)(g * 4) * DOUT + (w * 16 + c);
#pragma unroll
        for (int mt2 = 0; mt2 < 4; ++mt2) {
            f32x4 acc = {0.f, 0.f, 0.f, 0.f};
#pragma unroll
            for (int kb = 0; kb < 4; ++kb)
                acc = MFMA(Wt[mt2][kb], Bt[kb], acc);
#pragma unroll
            for (int r = 0; r < 4; ++r)
                ob[(size_t)(mt2 * 16 + r) * DOUT] = acc[r];
        }
    }
}

extern "C" void kernel_launch(void* const* d_in, const int* in_sizes, int n_in,
                              void* d_out, int out_size, void* d_ws, size_t ws_size,
                              hipStream_t stream)
{
    const float* x  = (const float*)d_in[0];   // (32,64,128,128) fp32
    const float* wv = (const float*)d_in[3];   // (128,64) fp32
    float* out = (float*)d_out;                // (2048,64,64) fp32

    (void)in_sizes; (void)n_in; (void)d_ws; (void)ws_size; (void)out_size;

    hipLaunchKernelGGL(spd_v8_kernel, dim3(GRID), dim3(BLOCK), 0, stream,
                       x, wv, out);
}